// Round 3
// baseline (2022.978 us; speedup 1.0000x reference)
//
#include <hip/hip_runtime.h>
#include <type_traits>

// LatentRecurrent persistent kernel R3: B=4096, Z=512, H=384, T=32, r=0.025
// 128 blocks x 1024 threads (16 waves, 4/SIMD). Block owns 32 rows for all 31 steps.
// LDS: zh f16 [32][520] (z mirror, GEMM1-A), tp f16 [32][776] (cols 0..383 = lrelu(zW1^T+b1),
//      cols 384..767 = h, updated in place), bias fp32. ~86 KB.
// z master fp32 lives in REGISTERS (wave w owns z-tile w, C/D-layout, 16 VGPRs).
// Weights pre-swizzled into per-lane fragment streams: frag f = ((nt*(K/16)+ks)*64+l),
// dst[f*8+e] = W[nt*32+(l&31)][ks*16+(l>>5)*8+e]  -> each wave reads sequential 1KB chunks.
// MFMA 32x32x16 f16; C/D: col=lane&31, row=(rg&3)+8*(rg>>2)+4*(lane>>5)  [m74/m101]

typedef _Float16 f16;
typedef f16 f16x8 __attribute__((ext_vector_type(8)));
typedef float f32x16 __attribute__((ext_vector_type(16)));

#define ZD 512
#define HD 384
#define TT 32
#define BM 32
#define LZH 520   // 260 words ≡ 4 mod 32 -> conflict-free b128 across 32 rows
#define LTP 776   // 388 words ≡ 4 mod 32

__device__ __forceinline__ float lrelu(float x) { return x >= 0.f ? x : 0.01f * x; }

// swizzle W[N][K] fp32 (row-major) -> fragment-stream f16
__global__ void swz(const float* __restrict__ W, f16* __restrict__ dst, int N, int K) {
    int nk = K >> 4;
    int total = (N >> 5) * nk * 64;
    for (int f = blockIdx.x * blockDim.x + threadIdx.x; f < total; f += gridDim.x * blockDim.x) {
        int l = f & 63, c = f >> 6;
        int ks = c % nk, nt = c / nk;
        const float* s = W + (size_t)(nt * 32 + (l & 31)) * K + ks * 16 + (l >> 5) * 8;
        f16* d = dst + (size_t)f * 8;
        #pragma unroll
        for (int e = 0; e < 8; ++e) d[e] = (f16)s[e];
    }
}

__global__ __launch_bounds__(1024, 4) void latrec(
    const float* __restrict__ z0g, const float* __restrict__ h0g,
    const f16* __restrict__ W1s, const f16* __restrict__ W23s,
    const float* __restrict__ b1g, const float* __restrict__ b2g, const float* __restrict__ b3g,
    float* __restrict__ out)
{
    __shared__ f16 zh[BM * LZH];
    __shared__ f16 tp[BM * LTP];
    __shared__ float bias[1280];  // b1@0, b2@384, b3@896

    const int tid = threadIdx.x;
    const int w = tid >> 6, l = tid & 63;
    const int lm = l & 31, lk8 = (l >> 5) * 8;
    const int m0 = blockIdx.x * BM;

    // ---- init ----
    for (int i = tid; i < HD; i += 1024) bias[i] = b1g[i];
    for (int i = tid; i < ZD; i += 1024) bias[HD + i] = b2g[i];
    for (int i = tid; i < HD; i += 1024) bias[896 + i] = b3g[i];
    for (int i = tid; i < BM * ZD; i += 1024) {
        int r = i >> 9, c = i & 511;
        float v = z0g[(size_t)(m0 + r) * ZD + c];
        zh[r * LZH + c] = (f16)v;
        out[((size_t)(m0 + r) * TT) * ZD + c] = 0.f;   // out[:,0,:] = 0
    }
    for (int i = tid; i < BM * HD; i += 1024) {
        int r = i / HD, c = i - r * HD;
        tp[r * LTP + HD + c] = (f16)h0g[(size_t)(m0 + r) * HD + c];
    }
    // z master fp32 in regs: wave w owns cols w*32+lm, rows per C/D map
    f32x16 zm;
    {
        int c = w * 32 + lm;
        #pragma unroll
        for (int rg = 0; rg < 16; ++rg) {
            int row = (rg & 3) + 8 * (rg >> 2) + 4 * (l >> 5);
            zm[rg] = z0g[(size_t)(m0 + row) * ZD + c];
        }
    }
    __syncthreads();

    const bool hash = (w < 4) || (w >= 8);          // waves with an h-tile in P2
    const int ht = (w < 4) ? w : (w - 4);           // h-tile id 0..11
    const f16* zbs = W23s + (size_t)w * 24576 + (size_t)l * 8;          // z-tile stream
    const f16* hbs = W23s + (size_t)(16 + ht) * 24576 + (size_t)l * 8;  // h-tile stream
    const float rr = 0.025f;

    for (int t = 1; t < TT; ++t) {
        // ================= P1: tp[:,0:384] = f16(lrelu(z @ W1^T + b1)) =================
        if (w < 12) {
            const f16* bs = W1s + (size_t)w * 16384 + (size_t)l * 8;
            const f16* ap = zh + lm * LZH + lk8;
            f32x16 acc = {};
            f16x8 b0 = *(const f16x8*)(bs);
            f16x8 b1 = *(const f16x8*)(bs + 512);
            f16x8 b2 = *(const f16x8*)(bs + 1024);
            #pragma unroll
            for (int ks = 0; ks < 32; ++ks) {
                f16x8 a = *(const f16x8*)(ap + ks * 16);
                f16x8 bn{};
                if (ks + 3 < 32) bn = *(const f16x8*)(bs + (size_t)(ks + 3) * 512);
                acc = __builtin_amdgcn_mfma_f32_32x32x16_f16(a, b0, acc, 0, 0, 0);
                b0 = b1; b1 = b2; b2 = bn;
            }
            int c = w * 32 + lm;
            float bv = bias[c];
            #pragma unroll
            for (int rg = 0; rg < 16; ++rg) {
                int row = (rg & 3) + 8 * (rg >> 2) + 4 * (l >> 5);
                tp[row * LTP + c] = (f16)lrelu(acc[rg] + bv);
            }
        }
        __syncthreads();   // (1) tz ready

        // ================= P2: fused GEMM2/3 over K=768 =================
        f32x16 az = {}, ah = {};
        {
            const f16* ap = tp + lm * LTP + lk8;
            auto kloop = [&](auto HASH) {
                f16x8 z0r = *(const f16x8*)(zbs);
                f16x8 z1r = *(const f16x8*)(zbs + 512);
                f16x8 z2r = *(const f16x8*)(zbs + 1024);
                f16x8 h0r{}, h1r{}, h2r{};
                if constexpr (decltype(HASH)::value) {
                    h0r = *(const f16x8*)(hbs);
                    h1r = *(const f16x8*)(hbs + 512);
                    h2r = *(const f16x8*)(hbs + 1024);
                }
                #pragma unroll
                for (int ks = 0; ks < 48; ++ks) {
                    f16x8 a = *(const f16x8*)(ap + ks * 16);
                    f16x8 zn{}, hn{};
                    if (ks + 3 < 48) {
                        zn = *(const f16x8*)(zbs + (size_t)(ks + 3) * 512);
                        if constexpr (decltype(HASH)::value)
                            hn = *(const f16x8*)(hbs + (size_t)(ks + 3) * 512);
                    }
                    az = __builtin_amdgcn_mfma_f32_32x32x16_f16(a, z0r, az, 0, 0, 0);
                    if constexpr (decltype(HASH)::value)
                        ah = __builtin_amdgcn_mfma_f32_32x32x16_f16(a, h0r, ah, 0, 0, 0);
                    z0r = z1r; z1r = z2r; z2r = zn;
                    if constexpr (decltype(HASH)::value) { h0r = h1r; h1r = h2r; h2r = hn; }
                }
            };
            if (hash) kloop(std::true_type{});
            else      kloop(std::false_type{});
        }

        // z epilogue (regs + zh + out) — touches nothing other waves read this step
        {
            int c = w * 32 + lm;
            float bv = bias[HD + c];
            #pragma unroll
            for (int rg = 0; rg < 16; ++rg) {
                int row = (rg & 3) + 8 * (rg >> 2) + 4 * (l >> 5);
                float v = lrelu(az[rg] + bv) * rr;
                float zn2 = zm[rg] + v;
                zm[rg] = zn2;
                zh[row * LZH + c] = (f16)zn2;
                size_t gr = (size_t)(m0 + row);
                float o = zn2 - z0g[gr * ZD + c];
                __builtin_nontemporal_store(o, out + (gr * TT + t) * ZD + c);
            }
        }
        __syncthreads();   // (2) all tp reads done -> safe to update h in place
        if (hash) {
            int c2 = ht * 32 + lm;
            float bv = bias[896 + c2];
            #pragma unroll
            for (int rg = 0; rg < 16; ++rg) {
                int row = (rg & 3) + 8 * (rg >> 2) + 4 * (l >> 5);
                float v = lrelu(ah[rg] + bv) * rr;
                int a = row * LTP + HD + c2;
                float hn2 = (float)tp[a] + v;
                tp[a] = (f16)hn2;
            }
        }
        __syncthreads();   // (3) zh + h ready for next step
    }
}

extern "C" void kernel_launch(void* const* d_in, const int* in_sizes, int n_in,
                              void* d_out, int out_size, void* d_ws, size_t ws_size,
                              hipStream_t stream) {
    const float* z  = (const float*)d_in[0];
    const float* h0 = (const float*)d_in[1];
    const float* W1 = (const float*)d_in[2];
    const float* b1 = (const float*)d_in[3];
    const float* W2 = (const float*)d_in[4];
    const float* b2 = (const float*)d_in[5];
    const float* W3 = (const float*)d_in[6];
    const float* b3 = (const float*)d_in[7];
    float* out = (float*)d_out;

    char* p = (char*)d_ws;
    f16* W1s  = (f16*)p; p += (size_t)HD * ZD * 2;                 // 12 tiles * 16384 f16
    f16* W23s = (f16*)p; p += (size_t)(ZD + HD) * 768 * 2;         // 28 tiles * 24576 f16

    swz<<<96, 256, 0, stream>>>(W1, W1s, HD, ZD);                  // 12*32*64 frags
    swz<<<192, 256, 0, stream>>>(W2, W23s, ZD, 768);               // tiles 0..15
    swz<<<144, 256, 0, stream>>>(W3, W23s + (size_t)16 * 24576, HD, 768); // tiles 16..27

    latrec<<<4096 / BM, 1024, 0, stream>>>(z, h0, W1s, W23s, b1, b2, b3, out);
}